// Round 1
// baseline (281.418 us; speedup 1.0000x reference)
//
#include <hip/hip_runtime.h>

#define B_ 2048
#define N_ 200
#define D_ 128
#define H_ 4
#define NE1 4   // NE+1
#define NN1 3   // NN+1

// ---------------------------------------------------------------------------
// Mask storage detection: if mask was stored as 1-byte bools, some 32-bit
// word in the first B*N bytes will have value > 1 (byte pattern). If it was
// stored as int32 (values 0/1), every word is 0 or 1. Writes flag to ws[0].
// ---------------------------------------------------------------------------
__global__ void detect_mask_kernel(const unsigned int* __restrict__ mw,
                                   int nwords, unsigned int* __restrict__ flag) {
  __shared__ int sbad;
  if (threadIdx.x == 0) sbad = 0;
  __syncthreads();
  int bad = 0;
  for (int i = blockIdx.x * blockDim.x + threadIdx.x; i < nwords;
       i += gridDim.x * blockDim.x)
    if (mw[i] > 1u) bad = 1;
  if (bad) sbad = 1;
  __syncthreads();
  if (threadIdx.x == 0 && sbad) atomicOr(flag, 1u);
}

// ---------------------------------------------------------------------------
// Fused kernel: one block per batch element b.
// ---------------------------------------------------------------------------
__global__ __launch_bounds__(256) void fused_mha_kernel(
    const float* __restrict__ q, const float* __restrict__ k,
    const float* __restrict__ v, const float* __restrict__ Wq,
    const float* __restrict__ Wk, const float* __restrict__ Wv,
    const float* __restrict__ rel_pri, const float* __restrict__ W_fc,
    const float* __restrict__ b_fc, const float* __restrict__ ln_gamma,
    const float* __restrict__ ln_beta, const int* __restrict__ etype,
    const int* __restrict__ utype, const void* __restrict__ maskp,
    const unsigned int* __restrict__ flag, float* __restrict__ y_out,
    float* __restrict__ attn_out) {
  const int b = blockIdx.x;
  const int tid = threadIdx.x;

  __shared__ float q_s[128];
  __shared__ float Qe_s[4][128];
  __shared__ float ehbuf[16][132];  // qM (scaled) during logits; s[] afterwards
  __shared__ float kv_s[64][132];   // k tile, then v tile
  __shared__ float p_s[4][200];     // logits -> probabilities
  __shared__ float msel[200];
  __shared__ int et_s[200];
  __shared__ float pri_s[16];       // [e*4+h]
  __shared__ float out_s[128];
  __shared__ float red_s[8];
  __shared__ int u_s;

  // ---------------- Phase 0: per-b metadata ----------------
  if (tid == 0) u_s = utype[b];
  if (tid < 128) q_s[tid] = q[(size_t)b * D_ + tid];
  const unsigned int isBool = flag[0];
  for (int i = tid; i < N_; i += 256) {
    et_s[i] = etype[(size_t)b * N_ + i];
    int m;
    if (isBool)
      m = ((const unsigned char*)maskp)[(size_t)b * N_ + i];
    else
      m = ((const int*)maskp)[(size_t)b * N_ + i];
    msel[i] = m ? 1.f : 0.f;
  }
  __syncthreads();
  if (tid < 16) {
    int e = tid >> 2, h = tid & 3;
    pri_s[tid] = rel_pri[(h * NN1 + u_s) * NE1 + e];  // rel_pri[h][u][e]
  }

  // ---------------- Phase 1: Qe[e][j] = Wq[e] @ q_b ----------------
  for (int idx = tid; idx < NE1 * 128; idx += 256) {
    int e = idx >> 7, j = idx & 127;
    const float4* wr = (const float4*)(Wq + (size_t)(e * 128 + j) * 128);
    const float4* qv = (const float4*)q_s;
    float acc = 0.f;
#pragma unroll 8
    for (int c = 0; c < 32; ++c) {
      float4 w = wr[c], qq = qv[c];
      acc += w.x * qq.x + w.y * qq.y + w.z * qq.z + w.w * qq.w;
    }
    Qe_s[e][j] = acc;
  }
  __syncthreads();

  // ------- Phase 2: qM[e,h,d] = sum_i Qe[e][h*32+i]*Wk[e][h*32+i][d] -------
  // folded scale: * pri[h,u,e] / sqrt(dk)
  const float rsdk = 0.17677669529663687f;  // 1/sqrt(32)
  for (int idx = tid; idx < 16 * 128; idx += 256) {
    int eh = idx >> 7, d = idx & 127;
    int e = eh >> 2, h = eh & 3;
    const float* wkb = Wk + ((size_t)(e * 128 + h * 32)) * 128 + d;
    float acc = 0.f;
#pragma unroll 8
    for (int i = 0; i < 32; ++i) acc += Qe_s[e][h * 32 + i] * wkb[i * 128];
    ehbuf[eh][d] = acc * pri_s[eh] * rsdk;
  }
  __syncthreads();

  // ---------------- Phase 3: logits = qM[e_n,h,:] . k[b,n,:] ----------------
  for (int t0 = 0; t0 < N_; t0 += 64) {
    int rows = (N_ - t0 < 64) ? (N_ - t0) : 64;
    for (int idx = tid; idx < rows * 32; idx += 256) {
      int r = idx >> 5, c = idx & 31;
      ((float4*)&kv_s[r][0])[c] =
          ((const float4*)(k + ((size_t)(b * N_ + t0 + r)) * D_))[c];
    }
    __syncthreads();
    for (int idx = tid; idx < rows * 4; idx += 256) {
      int nl = idx >> 2, h = idx & 3;
      int n = t0 + nl;
      int eh = et_s[n] * 4 + h;
      const float4* a = (const float4*)&ehbuf[eh][0];
      const float4* kk = (const float4*)&kv_s[nl][0];
      float acc = 0.f;
#pragma unroll 8
      for (int c = 0; c < 32; ++c) {
        float4 x = a[c], yv = kk[c];
        acc += x.x * yv.x + x.y * yv.y + x.z * yv.z + x.w * yv.w;
      }
      p_s[h][n] = (msel[n] > 0.5f) ? -1e10f : acc;
    }
    __syncthreads();
  }

  // ---------------- Phase 4: softmax over n, one wave per head ----------------
  {
    int w = tid >> 6, l = tid & 63;
    float mx = -1e30f;
    for (int n = l; n < N_; n += 64) mx = fmaxf(mx, p_s[w][n]);
#pragma unroll
    for (int o = 32; o; o >>= 1) mx = fmaxf(mx, __shfl_xor(mx, o));
    float sum = 0.f;
    for (int n = l; n < N_; n += 64) {
      float e = __expf(p_s[w][n] - mx);
      p_s[w][n] = e;
      sum += e;
    }
#pragma unroll
    for (int o = 32; o; o >>= 1) sum += __shfl_xor(sum, o);
    float inv = 1.f / sum;
    for (int n = l; n < N_; n += 64) {
      float pp = p_s[w][n] * inv;
      p_s[w][n] = pp;
      attn_out[((size_t)w * B_ + b) * N_ + n] = pp;
    }
  }
  __syncthreads();

  // ---------------- Phase 5: s[h][e][d] = sum_{n:e} p[h,n] * v[n,d] ----------------
  const int h5 = tid >> 6, d0 = tid & 63, d1 = 64 + (tid & 63);
  float a0[4] = {0.f, 0.f, 0.f, 0.f}, a1[4] = {0.f, 0.f, 0.f, 0.f};
  for (int t0 = 0; t0 < N_; t0 += 64) {
    int rows = (N_ - t0 < 64) ? (N_ - t0) : 64;
    for (int idx = tid; idx < rows * 32; idx += 256) {
      int r = idx >> 5, c = idx & 31;
      ((float4*)&kv_s[r][0])[c] =
          ((const float4*)(v + ((size_t)(b * N_ + t0 + r)) * D_))[c];
    }
    __syncthreads();
    for (int nl = 0; nl < rows; ++nl) {
      int n = t0 + nl;
      float pv = p_s[h5][n];
      float v0 = kv_s[nl][d0], v1 = kv_s[nl][d1];
      int en = et_s[n];
#pragma unroll
      for (int e = 0; e < 4; ++e) {
        float sel = (en == e) ? pv : 0.f;
        a0[e] = fmaf(sel, v0, a0[e]);
        a1[e] = fmaf(sel, v1, a1[e]);
      }
    }
    __syncthreads();
  }
  // stage s into ehbuf (qM no longer needed)
#pragma unroll
  for (int e = 0; e < 4; ++e) {
    ehbuf[e * 4 + h5][d0] = a0[e];
    ehbuf[e * 4 + h5][d1] = a1[e];
  }
  __syncthreads();

  // ---------------- Phase 6: out[h,j] = sum_e Wv[e][h*32+j][:] . s[h][e][:] ----------------
  if (tid < 128) {
    int h = tid >> 5, j = tid & 31;
    float acc = 0.f;
#pragma unroll
    for (int e = 0; e < 4; ++e) {
      const float4* wr =
          (const float4*)(Wv + ((size_t)(e * 128 + h * 32 + j)) * 128);
      const float4* ss = (const float4*)&ehbuf[e * 4 + h][0];
#pragma unroll 8
      for (int c = 0; c < 32; ++c) {
        float4 w = wr[c], sv = ss[c];
        acc += w.x * sv.x + w.y * sv.y + w.z * sv.z + w.w * sv.w;
      }
    }
    out_s[tid] = acc;
  }
  __syncthreads();

  // ---------------- Phase 7: FC (utype) + residual + LayerNorm ----------------
  float x = 0.f;
  {
    int u = u_s;
    if (tid < 128) {
      const float* wf = W_fc + (size_t)u * 128 * 128;
      float acc = b_fc[u * 128 + tid];
#pragma unroll 4
      for (int r = 0; r < 128; ++r) acc = fmaf(out_s[r], wf[r * 128 + tid], acc);
      x = acc + q_s[tid];
    }
  }
  float s1 = x, s2 = x * x;
#pragma unroll
  for (int o = 32; o; o >>= 1) {
    s1 += __shfl_xor(s1, o);
    s2 += __shfl_xor(s2, o);
  }
  if (tid < 128 && (tid & 63) == 0) {
    red_s[tid >> 6] = s1;
    red_s[4 + (tid >> 6)] = s2;
  }
  __syncthreads();
  if (tid < 128) {
    float t1 = red_s[0] + red_s[1], t2 = red_s[4] + red_s[5];
    float mu = t1 * (1.f / 128.f);
    float var = t2 * (1.f / 128.f) - mu * mu;
    float yv = (x - mu) * rsqrtf(var + 1e-5f) * ln_gamma[tid] + ln_beta[tid];
    y_out[(size_t)b * 128 + tid] = yv;
  }
}

extern "C" void kernel_launch(void* const* d_in, const int* in_sizes, int n_in,
                              void* d_out, int out_size, void* d_ws,
                              size_t ws_size, hipStream_t stream) {
  const float* q = (const float*)d_in[0];
  const float* k = (const float*)d_in[1];
  const float* v = (const float*)d_in[2];
  const float* Wq = (const float*)d_in[3];
  const float* Wk = (const float*)d_in[4];
  const float* Wv = (const float*)d_in[5];
  const float* rp = (const float*)d_in[6];
  const float* Wf = (const float*)d_in[7];
  const float* bf = (const float*)d_in[8];
  const float* g = (const float*)d_in[9];
  const float* be = (const float*)d_in[10];
  const int* et = (const int*)d_in[11];
  const int* ut = (const int*)d_in[12];
  const void* mask = d_in[13];

  float* y = (float*)d_out;
  float* attn = y + (size_t)B_ * D_;
  unsigned int* flag = (unsigned int*)d_ws;

  hipMemsetAsync(d_ws, 0, 4, stream);
  detect_mask_kernel<<<64, 256, 0, stream>>>((const unsigned int*)mask,
                                             B_ * N_ / 4, flag);
  fused_mha_kernel<<<B_, 256, 0, stream>>>(q, k, v, Wq, Wk, Wv, rp, Wf, bf, g,
                                           be, et, ut, mask, flag, y, attn);
}